// Round 3
// baseline (2056.975 us; speedup 1.0000x reference)
//
#include <hip/hip_runtime.h>
#include <hip/hip_cooperative_groups.h>
#include <math.h>

namespace cg = cooperative_groups;

// Problem: SEQ_LEN=512, BATCH=64, INPUT=256, HIDDEN=512. fp32 in/out.
#define TT 512
#define BB 64
#define II 256
#define HH 512

#define NTHREADS 512        // 8 waves
#define NGRP 4              // batch groups (16 rows each)
#define NCT  16             // h-tile blocks per group (32 h-units each)
#define NBLOCKS (NGRP*NCT)  // 64 blocks total

#define KPAD 776            // f16 elements per A row (768 + 8 pad; odd 16B-granule stride)

typedef _Float16 f16x8 __attribute__((ext_vector_type(8)));
typedef _Float16 f16x4 __attribute__((ext_vector_type(4)));
typedef float    f32x4 __attribute__((ext_vector_type(4)));

__device__ __forceinline__ float sig_(float v)  { return 1.0f / (1.0f + __expf(-v)); }
__device__ __forceinline__ float tanh_(float v) { float e = __expf(2.0f * v); return 1.0f - 2.0f / (e + 1.0f); }

// Barrier draining ONLY lgkmcnt — in-flight global stores stay off the chain.
__device__ __forceinline__ void barrier_lds() {
    __builtin_amdgcn_sched_barrier(0);
    asm volatile("s_waitcnt lgkmcnt(0)" ::: "memory");
    __builtin_amdgcn_s_barrier();
    __builtin_amdgcn_sched_barrier(0);
}
// Raw barrier: pure rendezvous (poll release), no counter drain at all.
__device__ __forceinline__ void barrier_raw() {
    __builtin_amdgcn_sched_barrier(0);
    asm volatile("" ::: "memory");
    __builtin_amdgcn_s_barrier();
    asm volatile("" ::: "memory");
    __builtin_amdgcn_sched_barrier(0);
}

__global__ void __launch_bounds__(NTHREADS, 2)
lstm_v4(const float* __restrict__ x,
        const float* __restrict__ Wx,
        const float* __restrict__ bx,
        const float* __restrict__ Wh,
        const float* __restrict__ bh,
        float* __restrict__ out,
        unsigned int* __restrict__ flags,   // [NGRP][16] u32: per-BLOCK epoch (one 64B line/group)
        unsigned int* __restrict__ hbuf)    // [2][NGRP][NCT][16 rows][16 pairs] u32
{
    // Double-buffered A tile (x | h): ONE lgkm barrier per step for staging.
    __shared__ __align__(16) _Float16 AL[2][16 * KPAD];   // 2 x 24,832 B
    __shared__ __align__(16) unsigned hvL[2][16][16];     // h_t gather, 2 KB

    cg::grid_group grid = cg::this_grid();

    const int blk  = blockIdx.x;
    const int grp  = blk & 3;          // batch group (16 rows)
    const int b0   = grp * 16;
    const int ct   = blk >> 2;         // 0..15, h-units [ct*32, ct*32+32)
    const int hblk = ct * 32;

    const int tid = threadIdx.x;
    const int wv  = tid >> 6;          // wave 0..7
    const int L   = tid & 63;
    const int n   = L & 15;
    const int qd  = L >> 4;            // k-octet

    // ---- Preload W fragments (constant all 512 steps). Used as MFMA *A* operand:
    // row m of A: gate g=m&3, h-unit hu=hblk+wv*4+(m>>2); per-lane m=n, k-octet=qd.
    f16x8 bfr[24];
    {
        const int g  = n & 3;
        const int hu = hblk + wv * 4 + (n >> 2);
        #pragma unroll
        for (int kc = 0; kc < 24; ++kc) {
            int k0 = kc * 32 + qd * 8;
            const float* src = (kc < 8)
                ? (Wx + ((size_t)g * HH + hu) * II + k0)
                : (Wh + ((size_t)g * HH + hu) * HH + (k0 - 256));
            float4 u0 = ((const float4*)src)[0];
            float4 u1 = ((const float4*)src)[1];
            f16x8 b = { (_Float16)u0.x, (_Float16)u0.y, (_Float16)u0.z, (_Float16)u0.w,
                        (_Float16)u1.x, (_Float16)u1.y, (_Float16)u1.z, (_Float16)u1.w };
            bfr[kc] = b;
        }
    }

    // Swapped-MFMA D layout: D[row=m][col=n_b], per-lane col=L&15, row=qd*4+reg.
    // => reg r = gate r of (batch be=n, h-unit he=hblk+wv*4+qd). No exchange needed.
    const int be = n;
    const int he = hblk + wv * 4 + qd;
    float bias4[4];
    #pragma unroll
    for (int g2 = 0; g2 < 4; ++g2) bias4[g2] = bx[g2 * HH + he] + bh[g2 * HH + he];

    // ---- Zero own flag; single full-grid sync ----
    if (tid == 0)
        __hip_atomic_store(&flags[grp * 16 + ct], 0u,
                           __ATOMIC_RELAXED, __HIP_MEMORY_SCOPE_AGENT);
    grid.sync();

    const size_t HSEQ = (size_t)TT * BB * HH;
    float c_state = 0.0f;

    for (int t = 0; t < TT; ++t) {
        const int p = t & 1;
        _Float16* ALp = AL[p];

        // ---- Stage x_t into x-part of current A buffer ----
        #pragma unroll
        for (int i = 0; i < 2; ++i) {
            int ch = tid + i * NTHREADS;           // 0..1023
            int row = ch >> 6, pos = ch & 63;
            float4 v = ((const float4*)(x + ((size_t)t * BB + b0 + row) * II))[pos];
            f16x4 pk = { (_Float16)v.x, (_Float16)v.y, (_Float16)v.z, (_Float16)v.w };
            *(f16x4*)&ALp[row * KPAD + pos * 4] = pk;
        }

        if (t > 0) {
            // ---- MINIMAL poll topology (v1-proven): wave0 only, one 64B line ----
            if (wv == 0) {
                const unsigned* fp = flags + grp * 16;
                const unsigned tu = (unsigned)t;
                for (;;) {
                    unsigned f = (L < NCT)
                        ? __hip_atomic_load(&fp[L], __ATOMIC_RELAXED, __HIP_MEMORY_SCOPE_AGENT)
                        : 0xFFFFFFFFu;
                    if (__all((int)(f >= tu))) break;
                    __builtin_amdgcn_s_sleep(1);
                }
            }
            barrier_raw();   // pure rendezvous: h_{t-1} now known visible

            // ---- Stage h_{t-1}: 16 coalesced 1KB producer chunks -> A h-part ----
            const unsigned long long* hsrc = (const unsigned long long*)
                (hbuf + ((size_t)p * NGRP + grp) * (NCT * 256));
            #pragma unroll
            for (int i = 0; i < 4; ++i) {
                int ch = tid + i * NTHREADS;       // 0..2047
                int row = (ch >> 7) & 15;          // batch row
                int q   = ch & 127;                // qword within row-slice
                int j   = q >> 3, sub = q & 7;     // producer chunk, qword in row
                unsigned long long u = __hip_atomic_load(
                    hsrc + (size_t)j * 128 + row * 8 + sub,
                    __ATOMIC_RELAXED, __HIP_MEMORY_SCOPE_AGENT);
                *(unsigned long long*)((char*)ALp + row * (KPAD * 2) + II * 2 + j * 64 + sub * 8) = u;
            }
        }

        // ---- Single staging barrier (lgkm only) ----
        barrier_lds();

        // ---- MFMA: W as A-operand, x/h as B-operand; 2 chains for ILP ----
        const char* Bb = (const char*)ALp + n * (KPAD * 2) + qd * 16;
        f32x4 a0 = { 0.f, 0.f, 0.f, 0.f };
        f32x4 a1 = { 0.f, 0.f, 0.f, 0.f };
        #pragma unroll
        for (int kc = 0; kc < 8; ++kc) {           // x-part
            f16x8 bf = *(const f16x8*)(Bb + kc * 64);
            if (kc & 1) a1 = __builtin_amdgcn_mfma_f32_16x16x32_f16(bfr[kc], bf, a1, 0, 0, 0);
            else        a0 = __builtin_amdgcn_mfma_f32_16x16x32_f16(bfr[kc], bf, a0, 0, 0, 0);
        }
        if (t > 0) {
            #pragma unroll
            for (int kc = 8; kc < 24; ++kc) {      // h-part
                f16x8 bf = *(const f16x8*)(Bb + kc * 64);
                if (kc & 1) a1 = __builtin_amdgcn_mfma_f32_16x16x32_f16(bfr[kc], bf, a1, 0, 0, 0);
                else        a0 = __builtin_amdgcn_mfma_f32_16x16x32_f16(bfr[kc], bf, a0, 0, 0, 0);
            }
        }
        f32x4 acc = a0 + a1;

        // ---- Gates straight from own registers (no LDS exchange) ----
        float fg = sig_(acc[0] + bias4[0]);
        float ig = sig_(acc[1] + bias4[1]);
        float og = sig_(acc[2] + bias4[2]);
        float cn = fg * c_state + ig * tanh_(acc[3] + bias4[3]);
        float hv = og * tanh_(cn);
        c_state = cn;

        if (t != TT - 1) {
            // ---- Gather h_t into LDS; wave7 alone publishes + flags ----
            union { _Float16 f; unsigned short u; } cv; cv.f = (_Float16)hv;
            unsigned mine  = cv.u;
            unsigned other = (unsigned)__shfl_xor((int)mine, 16, 64);  // partner qd^1
            if ((qd & 1) == 0)
                hvL[p][be][wv * 2 + (qd >> 1)] = mine | (other << 16);
            barrier_lds();   // gather visible to wave7

            if (wv == 7) {
                // lane L: chunk dwords L*4..L*4+3 = [row=L>>2][pairs (L&3)*4..]
                const unsigned* s = &hvL[p][0][0];
                uint4 v4 = *(const uint4*)(s + (L >> 2) * 16 + (L & 3) * 4);
                unsigned long long w0 = (unsigned long long)v4.x | ((unsigned long long)v4.y << 32);
                unsigned long long w1 = (unsigned long long)v4.z | ((unsigned long long)v4.w << 32);
                unsigned long long* dst = (unsigned long long*)
                    (hbuf + ((size_t)((t + 1) & 1) * NGRP + grp) * (NCT * 256) + ct * 256 + L * 4);
                __hip_atomic_store(dst + 0, w0, __ATOMIC_RELAXED, __HIP_MEMORY_SCOPE_AGENT);
                __hip_atomic_store(dst + 1, w1, __ATOMIC_RELAXED, __HIP_MEMORY_SCOPE_AGENT);
                // Drain ONLY this wave's stores (x/h loads long retired; out is
                // issued after the flag), then lane 0 publishes the epoch.
                __builtin_amdgcn_sched_barrier(0);
                asm volatile("s_waitcnt vmcnt(0)" ::: "memory");
                __builtin_amdgcn_sched_barrier(0);
                if (L == 0)
                    __hip_atomic_store(&flags[grp * 16 + ct], (unsigned)(t + 1),
                                       __ATOMIC_RELAXED, __HIP_MEMORY_SCOPE_AGENT);
            }
        }

        // ---- out stores AFTER flag publish: HBM acks off the critical chain ----
        out[((size_t)t * BB + b0 + be) * HH + he] = hv;
        if (t == TT - 1) {
            size_t r = (size_t)(b0 + be) * HH + he;
            out[HSEQ + r] = hv;                        // h_last
            out[HSEQ + (size_t)BB * HH + r] = cn;      // c_last
        }
        // No trailing barrier: A tile double-buffered (step t+1 writes AL[p^1],
        // which all waves finished reading before THIS step's staging barrier).
        // hbuf WAR guarded by flags: flag_i >= t+1 implies block i completed its
        // step-t reads of hbuf[t&1], which is the buffer overwritten at t+1.
    }
}

extern "C" void kernel_launch(void* const* d_in, const int* in_sizes, int n_in,
                              void* d_out, int out_size, void* d_ws, size_t ws_size,
                              hipStream_t stream)
{
    const float* x  = (const float*)d_in[0];
    const float* Wx = (const float*)d_in[1];
    const float* bx = (const float*)d_in[2];
    const float* Wh = (const float*)d_in[3];
    const float* bh = (const float*)d_in[4];
    float* out = (float*)d_out;

    // ws: [0,4KB) per-block epoch flags [NGRP][16]; [4KB, 4KB+128KB) h ping-pong
    unsigned int* flags = (unsigned int*)d_ws;
    unsigned int* hbuf  = (unsigned int*)((char*)d_ws + 4096);

    void* args[] = { (void*)&x, (void*)&Wx, (void*)&bx, (void*)&Wh, (void*)&bh,
                     (void*)&out, (void*)&flags, (void*)&hbuf };
    hipLaunchCooperativeKernel((const void*)lstm_v4,
                               dim3(NBLOCKS), dim3(NTHREADS),
                               args, 0, stream);
}

// Round 4
// 1862.864 us; speedup vs baseline: 1.1042x; 1.1042x over previous
//
#include <hip/hip_runtime.h>
#include <hip/hip_cooperative_groups.h>
#include <math.h>

namespace cg = cooperative_groups;

// Problem: SEQ_LEN=512, BATCH=64, INPUT=256, HIDDEN=512. fp32 in/out.
#define TT 512
#define BB 64
#define II 256
#define HH 512

#define NTHREADS 512        // 8 waves
#define NGRP 4              // batch groups (16 rows each)
#define NCT  16             // h-tile blocks per group (32 h-units each)
#define NBLOCKS (NGRP*NCT)  // 64 blocks total

#define KPAD 776            // f16 elements per A row (768 + 8 pad; 16B-granule stride 97, odd)

typedef _Float16 f16x8 __attribute__((ext_vector_type(8)));
typedef _Float16 f16x4 __attribute__((ext_vector_type(4)));
typedef float    f32x4 __attribute__((ext_vector_type(4)));
typedef unsigned int u32x4 __attribute__((ext_vector_type(4)));

__device__ __forceinline__ float sig_(float v)  { return 1.0f / (1.0f + __expf(-v)); }
__device__ __forceinline__ float tanh_(float v) { float e = __expf(2.0f * v); return 1.0f - 2.0f / (e + 1.0f); }

// Workgroup barrier that drains ONLY lgkmcnt (LDS) — no vmcnt(0), so in-flight
// global stores (h publish -> MALL, out -> HBM) never enter the critical chain.
__device__ __forceinline__ void barrier_lds() {
    __builtin_amdgcn_sched_barrier(0);
    asm volatile("s_waitcnt lgkmcnt(0)" ::: "memory");
    __builtin_amdgcn_s_barrier();
    __builtin_amdgcn_sched_barrier(0);
}

// {tag|f16},{tag|f16} 8B word -> packed f16 pair (low halves)
__device__ __forceinline__ unsigned pk2(unsigned long long q) {
    return (unsigned)(q & 0xffffULL) | (((unsigned)(q >> 32)) << 16);
}

__global__ void __launch_bounds__(NTHREADS, 2)
lstm_tag2(const float* __restrict__ x,
          const float* __restrict__ Wx,
          const float* __restrict__ bx,
          const float* __restrict__ Wh,
          const float* __restrict__ bh,
          float* __restrict__ out,
          unsigned int* __restrict__ hbuf)   // [2][BB][HH] u32: (tag<<16)|f16(h)
{
    // Double-buffered A tile (x | h) so ONE barrier/step suffices.
    __shared__ __align__(16) _Float16 AL[2][16 * KPAD];   // 2 x 24,832 B
    __shared__ __align__(16) float    exch[8 * 16 * 20];  // per-wave gate exchange

    cg::grid_group grid = cg::this_grid();

    const int blk  = blockIdx.x;
    const int grp  = blk & 3;          // batch group (16 rows)
    const int b0   = grp * 16;
    const int ct   = blk >> 2;         // 0..15, h-units [ct*32, ct*32+32)
    const int hblk = ct * 32;

    const int tid = threadIdx.x;
    const int wv  = tid >> 6;          // wave 0..7
    const int L   = tid & 63;
    const int n   = L & 15;            // MFMA A-row m / B-col n
    const int qd  = L >> 4;            // lane quad -> k = qd*8..qd*8+7

    // ---- Preload B fragments into registers; constant across ALL 512 steps ----
    const int g  = n & 3;
    const int hu = hblk + wv * 4 + (n >> 2);
    f16x8 bfr[24];
    #pragma unroll
    for (int kc = 0; kc < 24; ++kc) {
        int k0 = kc * 32 + qd * 8;
        const float* src = (kc < 8)
            ? (Wx + ((size_t)g * HH + hu) * II + k0)
            : (Wh + ((size_t)g * HH + hu) * HH + (k0 - 256));
        float4 u0 = ((const float4*)src)[0];
        float4 u1 = ((const float4*)src)[1];
        f16x8 b = { (_Float16)u0.x, (_Float16)u0.y, (_Float16)u0.z, (_Float16)u0.w,
                    (_Float16)u1.x, (_Float16)u1.y, (_Float16)u1.z, (_Float16)u1.w };
        bfr[kc] = b;
    }

    // Epilogue ownership: lane -> (batch be, h-unit he)
    const int be  = L >> 2;
    const int hle = L & 3;
    const int he  = hblk + wv * 4 + hle;
    float bias4[4];
    #pragma unroll
    for (int g2 = 0; g2 < 4; ++g2) bias4[g2] = bx[g2 * HH + he] + bh[g2 * HH + he];

    // ---- Zero OWN tagged slots in both buffers (tag 0 never matches t>=1) ----
    {
        unsigned idx = (unsigned)(b0 + be) * HH + (unsigned)he;
        __hip_atomic_store(&hbuf[idx], 0u,
                           __ATOMIC_RELAXED, __HIP_MEMORY_SCOPE_AGENT);
        __hip_atomic_store(&hbuf[(unsigned)(BB * HH) + idx], 0u,
                           __ATOMIC_RELAXED, __HIP_MEMORY_SCOPE_AGENT);
    }
    grid.sync();   // all tags zeroed before anyone can poll

    const size_t HSEQ = (size_t)TT * BB * HH;
    float c_state = 0.0f;
    float* exchW = &exch[wv * 16 * 20];

    // Poll/stage ownership: wave wv stages rows {wv*2, wv*2+1}, 16-col chunks.
    const int pr  = wv * 2 + (L >> 5);       // A row 0..15
    const int pc0 = (L & 31) * 16;           // col chunk base

    for (int t = 0; t < TT; ++t) {
        const int p = t & 1;
        _Float16* ALp = AL[p];

        // ---- Stage x_t into x-part of current A buffer ----
        #pragma unroll
        for (int i = 0; i < 2; ++i) {
            int ch = tid + i * NTHREADS;           // 0..1023
            int row = ch >> 6, pos = ch & 63;
            float4 v = ((const float4*)(x + ((size_t)t * BB + b0 + row) * II))[pos];
            f16x4 pk = { (_Float16)v.x, (_Float16)v.y, (_Float16)v.z, (_Float16)v.w };
            *(f16x4*)&ALp[row * KPAD + pos * 4] = pk;
        }

        // ---- Poll tagged h_{t-1} data directly (ONE round trip), stage to LDS ----
        if (t > 0) {
            const unsigned long long* sp =
                (const unsigned long long*)(hbuf + (size_t)p * (BB * HH))
                + (size_t)(b0 + pr) * (HH / 2) + (pc0 >> 1);
            const unsigned long long pat =
                ((unsigned long long)(unsigned)t << 16) |
                ((unsigned long long)(unsigned)t << 48);
            unsigned long long q0, q1, q2, q3, q4, q5, q6, q7;
            for (;;) {
                q0 = __hip_atomic_load(sp + 0, __ATOMIC_RELAXED, __HIP_MEMORY_SCOPE_AGENT);
                q1 = __hip_atomic_load(sp + 1, __ATOMIC_RELAXED, __HIP_MEMORY_SCOPE_AGENT);
                q2 = __hip_atomic_load(sp + 2, __ATOMIC_RELAXED, __HIP_MEMORY_SCOPE_AGENT);
                q3 = __hip_atomic_load(sp + 3, __ATOMIC_RELAXED, __HIP_MEMORY_SCOPE_AGENT);
                q4 = __hip_atomic_load(sp + 4, __ATOMIC_RELAXED, __HIP_MEMORY_SCOPE_AGENT);
                q5 = __hip_atomic_load(sp + 5, __ATOMIC_RELAXED, __HIP_MEMORY_SCOPE_AGENT);
                q6 = __hip_atomic_load(sp + 6, __ATOMIC_RELAXED, __HIP_MEMORY_SCOPE_AGENT);
                q7 = __hip_atomic_load(sp + 7, __ATOMIC_RELAXED, __HIP_MEMORY_SCOPE_AGENT);
                unsigned long long d = ((q0 ^ pat) | (q1 ^ pat) | (q2 ^ pat) | (q3 ^ pat) |
                                        (q4 ^ pat) | (q5 ^ pat) | (q6 ^ pat) | (q7 ^ pat))
                                       & 0xFFFF0000FFFF0000ULL;
                if (__all(d == 0ULL)) break;   // every tag == t exactly
                __builtin_amdgcn_s_sleep(1);   // *** backoff: keep this CU's VMEM
                                               // queue clear for its own publish
                                               // stores / x loads (v2 lacked this)
            }
            // strip tags, pack pairs, write 32B into h-part of A tile
            u32x4 P0 = { pk2(q0), pk2(q1), pk2(q2), pk2(q3) };
            u32x4 P1 = { pk2(q4), pk2(q5), pk2(q6), pk2(q7) };
            char* dst = (char*)ALp + pr * (KPAD * 2) + II * 2 + pc0 * 2;
            *(u32x4*)dst = P0;
            *(u32x4*)(dst + 16) = P1;
        }

        // ---- Single barrier per step (LDS-only drain; stores stay in flight) ----
        barrier_lds();

        // ---- MFMA: full K=768, two accumulator chains for ILP ----
        const char* Ab = (const char*)ALp + n * (KPAD * 2) + qd * 16;
        f32x4 a0 = { 0.f, 0.f, 0.f, 0.f };
        f32x4 a1 = { 0.f, 0.f, 0.f, 0.f };
        #pragma unroll
        for (int kc = 0; kc < 8; ++kc) {           // x-part
            f16x8 a = *(const f16x8*)(Ab + kc * 64);
            if (kc & 1) a1 = __builtin_amdgcn_mfma_f32_16x16x32_f16(a, bfr[kc], a1, 0, 0, 0);
            else        a0 = __builtin_amdgcn_mfma_f32_16x16x32_f16(a, bfr[kc], a0, 0, 0, 0);
        }
        if (t > 0) {
            #pragma unroll
            for (int kc = 8; kc < 24; ++kc) {      // h-part
                f16x8 a = *(const f16x8*)(Ab + kc * 64);
                if (kc & 1) a1 = __builtin_amdgcn_mfma_f32_16x16x32_f16(a, bfr[kc], a1, 0, 0, 0);
                else        a0 = __builtin_amdgcn_mfma_f32_16x16x32_f16(a, bfr[kc], a0, 0, 0, 0);
            }
        }
        f32x4 acc = a0 + a1;

        // ---- Intra-wave exchange: C[row=qd*4+r][col=n] -> gates per (b,h) ----
        #pragma unroll
        for (int r = 0; r < 4; ++r)
            exchW[(qd * 4 + r) * 20 + n] = acc[r];
        // same wave writes then reads: lockstep + in-order DS, no barrier needed
        float4 pre4 = *(const float4*)&exchW[be * 20 + hle * 4];

        // ---- Gates; c_state in-register ----
        float pf = pre4.x + bias4[0];
        float pi = pre4.y + bias4[1];
        float po = pre4.z + bias4[2];
        float pc = pre4.w + bias4[3];
        float fg = sig_(pf), ig = sig_(pi), og = sig_(po);
        float cn = fg * c_state + ig * tanh_(pc);
        float hv = og * tanh_(cn);
        c_state = cn;

        // ---- Publish h_t FIRST (tagged, self-validating; fire-and-forget) ----
        {
            union { _Float16 f; unsigned short u; } cv; cv.f = (_Float16)hv;
            unsigned val = ((unsigned)(t + 1) << 16) | (unsigned)cv.u;
            unsigned didx = (unsigned)((((t + 1) & 1) * BB + (b0 + be)) * HH + he);
            __hip_atomic_store(&hbuf[didx], val,
                               __ATOMIC_RELAXED, __HIP_MEMORY_SCOPE_AGENT);
        }

        out[((size_t)t * BB + b0 + be) * HH + he] = hv;
        if (t == TT - 1) {
            size_t r = (size_t)(b0 + be) * HH + he;
            out[HSEQ + r] = hv;                        // h_last
            out[HSEQ + (size_t)BB * HH + r] = cn;      // c_last
        }
        // no trailing barrier: A tile is double-buffered; next step's stage of
        // AL[p^1] is safe because all waves passed THIS step's barrier after
        // finishing their step-(t-1) MFMA reads of AL[p^1]. hbuf WAR safety:
        // a block can only reach step t+1's publish after reading every block's
        // step-t data, which implies all step-(t-1) readers of that buffer are done.
    }
}

extern "C" void kernel_launch(void* const* d_in, const int* in_sizes, int n_in,
                              void* d_out, int out_size, void* d_ws, size_t ws_size,
                              hipStream_t stream)
{
    const float* x  = (const float*)d_in[0];
    const float* Wx = (const float*)d_in[1];
    const float* bx = (const float*)d_in[2];
    const float* Wh = (const float*)d_in[3];
    const float* bh = (const float*)d_in[4];
    float* out = (float*)d_out;

    // ws: [0, 256KB) tagged-h ping-pong: [2][BB][HH] u32 = (tag<<16)|f16
    unsigned int* hbuf = (unsigned int*)d_ws;

    void* args[] = { (void*)&x, (void*)&Wx, (void*)&bx, (void*)&Wh, (void*)&bh,
                     (void*)&out, (void*)&hbuf };
    hipLaunchCooperativeKernel((const void*)lstm_tag2,
                               dim3(NBLOCKS), dim3(NTHREADS),
                               args, 0, stream);
}